// Round 13
// baseline (526.794 us; speedup 1.0000x reference)
//
#include <hip/hip_runtime.h>

#define HID 128
#define BN_EPS 1e-5f

typedef short bf16x8 __attribute__((ext_vector_type(8)));
typedef float f32x4 __attribute__((ext_vector_type(4)));

__device__ inline unsigned short f2b(float f) {  // f32 -> bf16 RNE
  unsigned int u = __float_as_uint(f);
  unsigned int r = (u + 0x7fffu + ((u >> 16) & 1u)) >> 16;
  return (unsigned short)r;
}
__device__ inline float bl(unsigned int v) { return __uint_as_float(v << 16); }
__device__ inline float bh(unsigned int v) { return __uint_as_float(v & 0xffff0000u); }

// Features stored as 2 channel-planes [2][N][64] bf16: row = 128B = exactly one
// cache line (full utilization), plane = 6.4MB. spmm slice = blockIdx&1 -> with
// round-robin block->XCD dispatch, each XCD's gather footprint is one plane.

// ---------------- bucketed CSR build (bucket = dst >> 8, 256 nodes/bucket) -------

__global__ void k_bhist(const int* __restrict__ dst, int* __restrict__ bcnt, int e, int nb) {
  __shared__ int h[256];
  for (int i = threadIdx.x; i < 256; i += blockDim.x) h[i] = 0;
  __syncthreads();
  int stride = gridDim.x * blockDim.x;
  for (int i = blockIdx.x * blockDim.x + threadIdx.x; i < e; i += stride)
    atomicAdd(&h[dst[i] >> 8], 1);
  __syncthreads();
  for (int i = threadIdx.x; i < nb; i += blockDim.x)
    if (h[i]) atomicAdd(&bcnt[i], h[i]);
}

// single block; nb <= 256
__global__ void k_bscan(const int* __restrict__ bcnt, int* __restrict__ base,
                        int* __restrict__ cur, int nb) {
  __shared__ int ws[4];
  int t = threadIdx.x;
  int v = (t < nb) ? bcnt[t] : 0;
  int lane = t & 63, wid = t >> 6;
  int x = v;
#pragma unroll
  for (int off = 1; off < 64; off <<= 1) {
    int y = __shfl_up(x, off, 64);
    if (lane >= off) x += y;
  }
  if (lane == 63) ws[wid] = x;
  __syncthreads();
  int add = 0;
  for (int w = 0; w < wid; ++w) add += ws[w];
  int incl = x + add;
  int excl = incl - v;
  if (t < nb) { base[t] = excl; cur[t] = excl; }
  if (t == nb - 1) base[nb] = incl;
}

__global__ void k_bscatter(const int* __restrict__ src, const int* __restrict__ dst,
                           int* __restrict__ cur, unsigned int* __restrict__ binned, int e) {
  __shared__ int bc[256];
  __shared__ int bo[256];
  int nchunk = (e + gridDim.x - 1) / gridDim.x;
  int c0 = blockIdx.x * nchunk;
  int c1 = min(c0 + nchunk, e);
  for (int i = threadIdx.x; i < 256; i += blockDim.x) bc[i] = 0;
  __syncthreads();
  for (int i = c0 + threadIdx.x; i < c1; i += blockDim.x)
    atomicAdd(&bc[dst[i] >> 8], 1);
  __syncthreads();
  for (int i = threadIdx.x; i < 256; i += blockDim.x) {
    int c = bc[i];
    bo[i] = c ? atomicAdd(&cur[i], c) : 0;
    bc[i] = 0;
  }
  __syncthreads();
  for (int i = c0 + threadIdx.x; i < c1; i += blockDim.x) {
    int d = dst[i];
    int b = d >> 8;
    int pos = bo[b] + atomicAdd(&bc[b], 1);
    binned[pos] = (unsigned)src[i] | ((unsigned)(d & 255) << 16);
  }
}

// one block per bucket: row_ptr, inv_deg, col — all scatters LDS/L2-local
__global__ __launch_bounds__(256) void k_bfill(
    const unsigned int* __restrict__ binned, const int* __restrict__ base,
    int* __restrict__ row_ptr, float* __restrict__ inv_deg,
    int* __restrict__ col, int n, int nb) {
  __shared__ int cnt[256];
  __shared__ int cur[256];
  __shared__ int ws[4];
  int b = blockIdx.x;
  int t = threadIdx.x;
  int n0 = b << 8;
  int e0 = base[b], e1 = base[b + 1];
  cnt[t] = 0;
  __syncthreads();
  for (int i = e0 + t; i < e1; i += 256)
    atomicAdd(&cnt[binned[i] >> 16], 1);
  __syncthreads();
  int v = cnt[t];
  int lane = t & 63, wid = t >> 6;
  int x = v;
#pragma unroll
  for (int off = 1; off < 64; off <<= 1) {
    int y = __shfl_up(x, off, 64);
    if (lane >= off) x += y;
  }
  if (lane == 63) ws[wid] = x;
  __syncthreads();
  int add = 0;
  for (int w = 0; w < wid; ++w) add += ws[w];
  int excl = x - v + add;
  int node = n0 + t;
  if (node < n) {
    row_ptr[node] = e0 + excl;
    inv_deg[node] = 1.0f / (float)max(v, 1);
  }
  cur[t] = e0 + excl;
  __syncthreads();
  for (int i = e0 + t; i < e1; i += 256) {
    unsigned int pr = binned[i];
    int pos = atomicAdd(&cur[pr >> 16], 1);
    col[pos] = (int)(pr & 0xffffu);
  }
  if (b == 0 && t == 0) row_ptr[n] = base[nb];
}

// ------- merged prep: x->bf16 planes, W->bf16 transposed, BN fold ---------------

__global__ void k_prep(const float* __restrict__ x, unsigned short* __restrict__ xb,
                       const float* __restrict__ Wl, const float* __restrict__ Wr,
                       unsigned short* __restrict__ Wlt, unsigned short* __restrict__ Wrt,
                       const float* __restrict__ g, const float* __restrict__ be,
                       const float* __restrict__ rm, const float* __restrict__ rv,
                       float* __restrict__ sc, float* __restrict__ sh,
                       int n4, int wtot, int bn, int ps) {
  int i = blockIdx.x * blockDim.x + threadIdx.x;
  if (i < n4) {
    float4 v = ((const float4*)x)[i];
    unsigned int lo = (unsigned int)f2b(v.x) | ((unsigned int)f2b(v.y) << 16);
    unsigned int hi = (unsigned int)f2b(v.z) | ((unsigned int)f2b(v.w) << 16);
    int flat = i << 2;
    int node = flat >> 7, c = flat & 127;
    *(uint2*)(xb + (size_t)(c >> 6) * ps + node * 64 + (c & 63)) = make_uint2(lo, hi);
  } else if (i < n4 + wtot) {
    int j = i - n4;
    int mat = j >> 14, rem = j & 16383, nn = rem >> 7, kk = rem & 127;
    int sidx = (mat << 14) + (kk << 7) + nn;
    Wlt[j] = f2b(Wl[sidx]);
    Wrt[j] = f2b(Wr[sidx]);
  } else if (i < n4 + wtot + bn) {
    int j = i - n4 - wtot;
    float s = g[j] * rsqrtf(rv[j] + BN_EPS);
    sc[j] = s;
    sh[j] = be[j] - rm[j] * s;
  }
}

// ------------- SpMM gather, 2 slices of 64ch (one full line per edge) -----------
// slice = blockIdx&1; wave = one node x one slice; 8 edge-slots x 8 ch-lanes.

__global__ __launch_bounds__(128) void k_spmm_g(
    const unsigned short* __restrict__ hbsrc, const int* __restrict__ row_ptr,
    const int* __restrict__ col, const float* __restrict__ inv_deg,
    unsigned short* __restrict__ aggb, int n, int ps) {
  int bid = blockIdx.x;
  int slice = bid & 1;
  int node = (bid >> 1) * 2 + (threadIdx.x >> 6);
  if (node >= n) return;
  int lane = threadIdx.x & 63;
  int slot = lane >> 3, c8 = lane & 7;
  int beg = row_ptr[node], end = row_ptr[node + 1];
  const unsigned short* base = hbsrc + (size_t)slice * ps + (c8 << 3);
  float a0 = 0, a1 = 0, a2 = 0, a3 = 0, a4 = 0, a5 = 0, a6 = 0, a7 = 0;
  int e = beg;
  for (; e + 16 <= end; e += 16) {
    int s0 = __builtin_nontemporal_load(&col[e + slot]);
    int s1 = __builtin_nontemporal_load(&col[e + 8 + slot]);
    uint4 v0 = *(const uint4*)(base + (size_t)s0 * 64);
    uint4 v1 = *(const uint4*)(base + (size_t)s1 * 64);
    a0 += bl(v0.x); a1 += bh(v0.x); a2 += bl(v0.y); a3 += bh(v0.y);
    a4 += bl(v0.z); a5 += bh(v0.z); a6 += bl(v0.w); a7 += bh(v0.w);
    a0 += bl(v1.x); a1 += bh(v1.x); a2 += bl(v1.y); a3 += bh(v1.y);
    a4 += bl(v1.z); a5 += bh(v1.z); a6 += bl(v1.w); a7 += bh(v1.w);
  }
  for (; e + 8 <= end; e += 8) {
    int s0 = __builtin_nontemporal_load(&col[e + slot]);
    uint4 v0 = *(const uint4*)(base + (size_t)s0 * 64);
    a0 += bl(v0.x); a1 += bh(v0.x); a2 += bl(v0.y); a3 += bh(v0.y);
    a4 += bl(v0.z); a5 += bh(v0.z); a6 += bl(v0.w); a7 += bh(v0.w);
  }
  {
    int idx = e + slot;
    if (idx < end) {
      int s = __builtin_nontemporal_load(&col[idx]);
      uint4 v = *(const uint4*)(base + (size_t)s * 64);
      a0 += bl(v.x); a1 += bh(v.x); a2 += bl(v.y); a3 += bh(v.y);
      a4 += bl(v.z); a5 += bh(v.z); a6 += bl(v.w); a7 += bh(v.w);
    }
  }
#pragma unroll
  for (int st = 8; st <= 32; st <<= 1) {
    a0 += __shfl_xor(a0, st); a1 += __shfl_xor(a1, st);
    a2 += __shfl_xor(a2, st); a3 += __shfl_xor(a3, st);
    a4 += __shfl_xor(a4, st); a5 += __shfl_xor(a5, st);
    a6 += __shfl_xor(a6, st); a7 += __shfl_xor(a7, st);
  }
  if (slot == 0) {
    float w = inv_deg[node];
    unsigned int p0 = (unsigned int)f2b(a0 * w) | ((unsigned int)f2b(a1 * w) << 16);
    unsigned int p1 = (unsigned int)f2b(a2 * w) | ((unsigned int)f2b(a3 * w) << 16);
    unsigned int p2 = (unsigned int)f2b(a4 * w) | ((unsigned int)f2b(a5 * w) << 16);
    unsigned int p3 = (unsigned int)f2b(a6 * w) | ((unsigned int)f2b(a7 * w) << 16);
    *(uint4*)(aggb + (size_t)slice * ps + node * 64 + (c8 << 3)) = make_uint4(p0, p1, p2, p3);
  }
}

// ---- MFMA layer GEMM, weight-stationary, 2 node-groups/iter, fused BN+ReLU -----
// reads/writes the [2][N][64] plane layout.

__global__ __launch_bounds__(256) void k_gemm3(
    const unsigned short* __restrict__ aggb,  // [2][N][64] bf16
    const unsigned short* __restrict__ hbsrc, // [2][N][64] bf16
    const unsigned short* __restrict__ Wlt,   // [128][128] bf16 [out_ch][k]
    const unsigned short* __restrict__ Wrt,
    const float* __restrict__ bias, const float* __restrict__ sc,
    const float* __restrict__ sh, unsigned short* __restrict__ hbo,
    int n, int ngroups, int ps) {
  int w = threadIdx.x >> 6;
  int lane = threadIdx.x & 63;
  int l15 = lane & 15, lhi = lane >> 4;

  bf16x8 aL[2][4], aR[2][4];
#pragma unroll
  for (int ms = 0; ms < 2; ++ms) {
    int row = (w << 5) + (ms << 4) + l15;
#pragma unroll
    for (int ks = 0; ks < 4; ++ks) {
      aL[ms][ks] = *(const bf16x8*)(Wlt + (row << 7) + (ks << 5) + (lhi << 3));
      aR[ms][ks] = *(const bf16x8*)(Wrt + (row << 7) + (ks << 5) + (lhi << 3));
    }
  }
  float4 bi[2], scv[2], shv[2];
#pragma unroll
  for (int ms = 0; ms < 2; ++ms) {
    int ch = (w << 5) + (ms << 4) + (lhi << 2);
    bi[ms] = *(const float4*)(bias + ch);
    scv[ms] = *(const float4*)(sc + ch);
    shv[ms] = *(const float4*)(sh + ch);
  }

  for (int g0 = blockIdx.x * 2; g0 < ngroups; g0 += gridDim.x * 2) {
    int g1 = g0 + 1;
    int nodeA = (g0 << 4) + l15;
    bool okA = nodeA < n;
    bool okB = (g1 < ngroups);
    int nodeB = okB ? (g1 << 4) + l15 : nodeA;
    okB = okB && nodeB < n;
    int nsA = okA ? nodeA : 0;
    int nsB = okB ? nodeB : 0;
    bf16x8 bA[4], bH[4], cA[4], cH[4];
#pragma unroll
    for (int ks = 0; ks < 4; ++ks) {
      // channel range [ks*32, ks*32+32): plane = ks>>1, in-plane off = (ks&1)*32 + lhi*8
      size_t po = (size_t)(ks >> 1) * ps + ((ks & 1) << 5) + (lhi << 3);
      bA[ks] = *(const bf16x8*)(aggb + po + nsA * 64);
      bH[ks] = *(const bf16x8*)(hbsrc + po + nsA * 64);
      cA[ks] = *(const bf16x8*)(aggb + po + nsB * 64);
      cH[ks] = *(const bf16x8*)(hbsrc + po + nsB * 64);
    }
    f32x4 acc0[2], acc1[2];
#pragma unroll
    for (int ms = 0; ms < 2; ++ms) { acc0[ms] = (f32x4)(0.f); acc1[ms] = (f32x4)(0.f); }
#pragma unroll
    for (int ms = 0; ms < 2; ++ms) {
#pragma unroll
      for (int ks = 0; ks < 4; ++ks) {
        acc0[ms] = __builtin_amdgcn_mfma_f32_16x16x32_bf16(aL[ms][ks], bA[ks], acc0[ms], 0, 0, 0);
        acc1[ms] = __builtin_amdgcn_mfma_f32_16x16x32_bf16(aL[ms][ks], cA[ks], acc1[ms], 0, 0, 0);
      }
#pragma unroll
      for (int ks = 0; ks < 4; ++ks) {
        acc0[ms] = __builtin_amdgcn_mfma_f32_16x16x32_bf16(aR[ms][ks], bH[ks], acc0[ms], 0, 0, 0);
        acc1[ms] = __builtin_amdgcn_mfma_f32_16x16x32_bf16(aR[ms][ks], cH[ks], acc1[ms], 0, 0, 0);
      }
    }
#pragma unroll
    for (int ms = 0; ms < 2; ++ms) {
      // out channel ch = w*32 + ms*16 + lhi*4: plane = w>>1, in-plane = (w&1)*32+ms*16+lhi*4
      size_t dof = (size_t)(w >> 1) * ps + ((w & 1) << 5) + (ms << 4) + (lhi << 2);
      if (okA) {
        float o0 = fmaxf((acc0[ms][0] + bi[ms].x) * scv[ms].x + shv[ms].x, 0.f);
        float o1 = fmaxf((acc0[ms][1] + bi[ms].y) * scv[ms].y + shv[ms].y, 0.f);
        float o2 = fmaxf((acc0[ms][2] + bi[ms].z) * scv[ms].z + shv[ms].z, 0.f);
        float o3 = fmaxf((acc0[ms][3] + bi[ms].w) * scv[ms].w + shv[ms].w, 0.f);
        unsigned int lo = (unsigned int)f2b(o0) | ((unsigned int)f2b(o1) << 16);
        unsigned int hi = (unsigned int)f2b(o2) | ((unsigned int)f2b(o3) << 16);
        *(uint2*)(hbo + dof + nodeA * 64) = make_uint2(lo, hi);
      }
      if (okB) {
        float o0 = fmaxf((acc1[ms][0] + bi[ms].x) * scv[ms].x + shv[ms].x, 0.f);
        float o1 = fmaxf((acc1[ms][1] + bi[ms].y) * scv[ms].y + shv[ms].y, 0.f);
        float o2 = fmaxf((acc1[ms][2] + bi[ms].z) * scv[ms].z + shv[ms].z, 0.f);
        float o3 = fmaxf((acc1[ms][3] + bi[ms].w) * scv[ms].w + shv[ms].w, 0.f);
        unsigned int lo = (unsigned int)f2b(o0) | ((unsigned int)f2b(o1) << 16);
        unsigned int hi = (unsigned int)f2b(o2) | ((unsigned int)f2b(o3) << 16);
        *(uint2*)(hbo + dof + nodeB * 64) = make_uint2(lo, hi);
      }
    }
  }
}

// ---------------- final layer ----------------

__global__ void k_pq(const unsigned short* __restrict__ hb, const float* __restrict__ Wl_out,
                     const float* __restrict__ Wr_out, float* __restrict__ p,
                     float* __restrict__ q, int n, int ps) {
  int node = blockIdx.x * 4 + (threadIdx.x >> 6);
  if (node >= n) return;
  int lane = threadIdx.x & 63;
  int c = lane << 1;  // channels c, c+1
  unsigned int hv = *(const unsigned int*)(hb + (size_t)(c >> 6) * ps + node * 64 + (c & 63));
  float hx = bl(hv), hy = bh(hv);
  float4 wl = *(const float4*)(Wl_out + (lane << 2)); // rows 2l,2l+1; cols 0,1
  float4 wr = *(const float4*)(Wr_out + (lane << 2));
  float p0 = hx * wl.x + hy * wl.z;
  float p1 = hx * wl.y + hy * wl.w;
  float q0 = hx * wr.x + hy * wr.z;
  float q1 = hx * wr.y + hy * wr.w;
#pragma unroll
  for (int off = 32; off > 0; off >>= 1) {
    p0 += __shfl_xor(p0, off, 64);
    p1 += __shfl_xor(p1, off, 64);
    q0 += __shfl_xor(q0, off, 64);
    q1 += __shfl_xor(q1, off, 64);
  }
  if (lane == 0) {
    *(float2*)(p + (size_t)node * 2) = make_float2(p0, p1);
    *(float2*)(q + (size_t)node * 2) = make_float2(q0, q1);
  }
}

// fused: per-node final conv output + segmented-scan mean-pool (batch is sorted)
__global__ void k_spmm2p(const float* __restrict__ p, const float* __restrict__ q,
                         const int* __restrict__ row_ptr, const int* __restrict__ col,
                         const float* __restrict__ inv_deg, const float* __restrict__ b_out,
                         const int* __restrict__ batch, float* __restrict__ out,
                         float* __restrict__ gcnt, int n) {
  int i = blockIdx.x * blockDim.x + threadIdx.x;
  int lane = threadIdx.x & 63;
  bool valid = i < n;
  float o0 = 0.f, o1 = 0.f;
  int g = -1;
  if (valid) {
    int beg = row_ptr[i], end = row_ptr[i + 1];
    float a0 = 0.f, a1 = 0.f, b0 = 0.f, b1 = 0.f;
    int e = beg;
    for (; e + 2 <= end; e += 2) {
      float2 v0 = *(const float2*)(p + (size_t)col[e] * 2);
      float2 v1 = *(const float2*)(p + (size_t)col[e + 1] * 2);
      a0 += v0.x; a1 += v0.y; b0 += v1.x; b1 += v1.y;
    }
    if (e < end) {
      float2 v = *(const float2*)(p + (size_t)col[e] * 2);
      a0 += v.x; a1 += v.y;
    }
    float w = inv_deg[i];
    float2 qv = *(const float2*)(q + (size_t)i * 2);
    o0 = (a0 + b0) * w + qv.x + b_out[0];
    o1 = (a1 + b1) * w + qv.y + b_out[1];
    g = batch[i];
  }
  float s0 = o0, s1 = o1;
#pragma unroll
  for (int off = 1; off < 64; off <<= 1) {
    float y0 = __shfl_up(s0, off, 64);
    float y1 = __shfl_up(s1, off, 64);
    if (lane >= off) { s0 += y0; s1 += y1; }
  }
  int gprev = __shfl_up(g, 1, 64);
  int gnext = __shfl_down(g, 1, 64);
  bool is_start = (lane == 0) || (g != gprev);
  bool is_end = valid && ((lane == 63) || (g != gnext));
  int startl = is_start ? lane : 0;
#pragma unroll
  for (int off = 1; off < 64; off <<= 1) {
    int y = __shfl_up(startl, off, 64);
    if (lane >= off) startl = max(startl, y);
  }
  int prevl = startl > 0 ? startl - 1 : 0;
  float t0 = __shfl(s0, prevl, 64);
  float t1 = __shfl(s1, prevl, 64);
  if (is_end) {
    float p0 = startl > 0 ? t0 : 0.f;
    float p1 = startl > 0 ? t1 : 0.f;
    atomicAdd(&out[g * 2], s0 - p0);
    atomicAdd(&out[g * 2 + 1], s1 - p1);
    atomicAdd(&gcnt[g], (float)(lane - startl + 1));
  }
}

__global__ void k_div(float* __restrict__ out, const float* __restrict__ gcnt, int ng) {
  int i = blockIdx.x * blockDim.x + threadIdx.x;
  if (i < ng * 2) out[i] /= fmaxf(gcnt[i >> 1], 1.0f);
}

// ---------------- launch ----------------

extern "C" void kernel_launch(void* const* d_in, const int* in_sizes, int n_in,
                              void* d_out, int out_size, void* d_ws, size_t ws_size,
                              hipStream_t stream) {
  const float* x = (const float*)d_in[0];
  const float* Wl = (const float*)d_in[1];
  const float* Wr = (const float*)d_in[2];
  const float* b = (const float*)d_in[3];
  const float* gamma = (const float*)d_in[4];
  const float* beta = (const float*)d_in[5];
  const float* rmean = (const float*)d_in[6];
  const float* rvar = (const float*)d_in[7];
  const float* Wl_out = (const float*)d_in[8];
  const float* Wr_out = (const float*)d_in[9];
  const float* b_out = (const float*)d_in[10];
  const int* eidx = (const int*)d_in[11];
  const int* batch = (const int*)d_in[12];

  const int N = in_sizes[0] / HID;
  const int E = in_sizes[11] / 2;
  const int L = in_sizes[1] / (HID * HID);
  const int NG = out_size / 2;
  const int NB = (N + 255) >> 8;  // nodes/bucket = 256; requires N <= 65536
  const int NGRP = (N + 15) >> 4;
  const int PS = N * 64;          // plane stride (elements)
  const int* src = eidx;
  const int* dst = eidx + E;

  char* ws = (char*)d_ws;
  size_t off = 0;
  auto alloc = [&](size_t bytes) {
    void* ptr = ws + off;
    off += (bytes + 255) & ~(size_t)255;
    return ptr;
  };
  int* row_ptr = (int*)alloc((size_t)(N + 1) * 4);
  int* bcnt = (int*)alloc((size_t)NB * 4);
  int* bbase = (int*)alloc((size_t)(NB + 1) * 4);
  int* bcur = (int*)alloc((size_t)NB * 4);
  int* col = (int*)alloc((size_t)E * 4);
  float* inv_deg = (float*)alloc((size_t)N * 4);
  unsigned short* xb = (unsigned short*)alloc((size_t)N * HID * 2);
  unsigned short* hb0 = (unsigned short*)alloc((size_t)N * HID * 2);
  unsigned short* hb1 = (unsigned short*)alloc((size_t)N * HID * 2);
  unsigned short* aggb = (unsigned short*)alloc((size_t)N * HID * 2);
  unsigned short* Wlt = (unsigned short*)alloc((size_t)L * HID * HID * 2);
  unsigned short* Wrt = (unsigned short*)alloc((size_t)L * HID * HID * 2);
  float* sc = (float*)alloc((size_t)L * HID * 4);
  float* sh = (float*)alloc((size_t)L * HID * 4);
  float* p = (float*)alloc((size_t)N * 2 * 4);
  float* q = (float*)alloc((size_t)N * 2 * 4);
  float* gcnt = (float*)alloc((size_t)NG * 4);
  unsigned int* binned = (unsigned int*)alloc((size_t)E * 4);  // dead after k_bfill

  hipMemsetAsync(bcnt, 0, (size_t)NB * 4, stream);
  k_bhist<<<256, 256, 0, stream>>>(dst, bcnt, E, NB);
  k_bscan<<<1, 256, 0, stream>>>(bcnt, bbase, bcur, NB);
  k_bscatter<<<256, 256, 0, stream>>>(src, dst, bcur, binned, E);
  k_bfill<<<NB, 256, 0, stream>>>(binned, bbase, row_ptr, inv_deg, col, N, NB);

  const int n4 = N * HID / 4;
  const int wtot = L * HID * HID;
  const int bn = L * HID;
  k_prep<<<(n4 + wtot + bn + 255) / 256, 256, 0, stream>>>(
      x, xb, Wl, Wr, Wlt, Wrt, gamma, beta, rmean, rvar, sc, sh, n4, wtot, bn, PS);

  const unsigned short* hin = xb;
  for (int l = 0; l < L; ++l) {
    unsigned short* hnext = (l & 1) ? hb1 : hb0;
    k_spmm_g<<<2 * ((N + 1) / 2), 128, 0, stream>>>(hin, row_ptr, col, inv_deg, aggb, N, PS);
    k_gemm3<<<512, 256, 0, stream>>>(
        aggb, hin, Wlt + (size_t)l * HID * HID, Wrt + (size_t)l * HID * HID,
        b + (size_t)l * HID, sc + (size_t)l * HID, sh + (size_t)l * HID,
        hnext, N, NGRP, PS);
    hin = hnext;
  }
  k_pq<<<(N + 3) / 4, 256, 0, stream>>>(hin, Wl_out, Wr_out, p, q, N, PS);
  hipMemsetAsync(d_out, 0, (size_t)out_size * 4, stream);
  hipMemsetAsync(gcnt, 0, (size_t)NG * 4, stream);
  k_spmm2p<<<(N + 255) / 256, 256, 0, stream>>>(
      p, q, row_ptr, col, inv_deg, b_out, batch, (float*)d_out, gcnt, N);
  k_div<<<(NG * 2 + 255) / 256, 256, 0, stream>>>((float*)d_out, gcnt, NG);
}

// Round 14
// 499.313 us; speedup vs baseline: 1.0550x; 1.0550x over previous
//
#include <hip/hip_runtime.h>

#define HID 128
#define BN_EPS 1e-5f

typedef short bf16x8 __attribute__((ext_vector_type(8)));
typedef float f32x4 __attribute__((ext_vector_type(4)));

__device__ inline unsigned short f2b(float f) {  // f32 -> bf16 RNE
  unsigned int u = __float_as_uint(f);
  unsigned int r = (u + 0x7fffu + ((u >> 16) & 1u)) >> 16;
  return (unsigned short)r;
}
__device__ inline float bl(unsigned int v) { return __uint_as_float(v << 16); }
__device__ inline float bh(unsigned int v) { return __uint_as_float(v & 0xffff0000u); }

// ---------------- bucketed CSR build (bucket = dst >> 8, 256 nodes/bucket) -------

__global__ void k_bhist(const int* __restrict__ dst, int* __restrict__ bcnt, int e, int nb) {
  __shared__ int h[256];
  for (int i = threadIdx.x; i < 256; i += blockDim.x) h[i] = 0;
  __syncthreads();
  int stride = gridDim.x * blockDim.x;
  for (int i = blockIdx.x * blockDim.x + threadIdx.x; i < e; i += stride)
    atomicAdd(&h[dst[i] >> 8], 1);
  __syncthreads();
  for (int i = threadIdx.x; i < nb; i += blockDim.x)
    if (h[i]) atomicAdd(&bcnt[i], h[i]);
}

// single block; nb <= 256
__global__ void k_bscan(const int* __restrict__ bcnt, int* __restrict__ base,
                        int* __restrict__ cur, int nb) {
  __shared__ int ws[4];
  int t = threadIdx.x;
  int v = (t < nb) ? bcnt[t] : 0;
  int lane = t & 63, wid = t >> 6;
  int x = v;
#pragma unroll
  for (int off = 1; off < 64; off <<= 1) {
    int y = __shfl_up(x, off, 64);
    if (lane >= off) x += y;
  }
  if (lane == 63) ws[wid] = x;
  __syncthreads();
  int add = 0;
  for (int w = 0; w < wid; ++w) add += ws[w];
  int incl = x + add;
  int excl = incl - v;
  if (t < nb) { base[t] = excl; cur[t] = excl; }
  if (t == nb - 1) base[nb] = incl;
}

__global__ void k_bscatter(const int* __restrict__ src, const int* __restrict__ dst,
                           int* __restrict__ cur, uint2* __restrict__ binned, int e) {
  __shared__ int bc[256];
  __shared__ int bo[256];
  int nchunk = (e + gridDim.x - 1) / gridDim.x;
  int c0 = blockIdx.x * nchunk;
  int c1 = min(c0 + nchunk, e);
  for (int i = threadIdx.x; i < 256; i += blockDim.x) bc[i] = 0;
  __syncthreads();
  for (int i = c0 + threadIdx.x; i < c1; i += blockDim.x)
    atomicAdd(&bc[dst[i] >> 8], 1);
  __syncthreads();
  for (int i = threadIdx.x; i < 256; i += blockDim.x) {
    int c = bc[i];
    bo[i] = c ? atomicAdd(&cur[i], c) : 0;
    bc[i] = 0;
  }
  __syncthreads();
  for (int i = c0 + threadIdx.x; i < c1; i += blockDim.x) {
    int d = dst[i];
    int b = d >> 8;
    int pos = bo[b] + atomicAdd(&bc[b], 1);
    binned[pos] = make_uint2((unsigned)src[i], (unsigned)d);
  }
}

// one block per bucket: row_ptr, inv_deg, col — all scatters LDS/L2-local
__global__ __launch_bounds__(256) void k_bfill(
    const uint2* __restrict__ binned, const int* __restrict__ base,
    int* __restrict__ row_ptr, float* __restrict__ inv_deg,
    int* __restrict__ col, int n, int nb) {
  __shared__ int cnt[256];
  __shared__ int cur[256];
  __shared__ int ws[4];
  int b = blockIdx.x;
  int t = threadIdx.x;
  int n0 = b << 8;
  int e0 = base[b], e1 = base[b + 1];
  cnt[t] = 0;
  __syncthreads();
  for (int i = e0 + t; i < e1; i += 256)
    atomicAdd(&cnt[binned[i].y & 255], 1);
  __syncthreads();
  int v = cnt[t];
  int lane = t & 63, wid = t >> 6;
  int x = v;
#pragma unroll
  for (int off = 1; off < 64; off <<= 1) {
    int y = __shfl_up(x, off, 64);
    if (lane >= off) x += y;
  }
  if (lane == 63) ws[wid] = x;
  __syncthreads();
  int add = 0;
  for (int w = 0; w < wid; ++w) add += ws[w];
  int excl = x - v + add;
  int node = n0 + t;
  if (node < n) {
    row_ptr[node] = e0 + excl;
    inv_deg[node] = 1.0f / (float)max(v, 1);
  }
  cur[t] = e0 + excl;
  __syncthreads();
  for (int i = e0 + t; i < e1; i += 256) {
    uint2 pr = binned[i];
    int pos = atomicAdd(&cur[pr.y & 255], 1);
    col[pos] = (int)pr.x;
  }
  if (b == 0 && t == 0) row_ptr[n] = base[nb];
}

// ------- merged prep: x->bf16, W->bf16 transposed, BN fold (one launch) ---------

__global__ void k_prep(const float* __restrict__ x, unsigned short* __restrict__ xb,
                       const float* __restrict__ Wl, const float* __restrict__ Wr,
                       unsigned short* __restrict__ Wlt, unsigned short* __restrict__ Wrt,
                       const float* __restrict__ g, const float* __restrict__ be,
                       const float* __restrict__ rm, const float* __restrict__ rv,
                       float* __restrict__ sc, float* __restrict__ sh,
                       int n4, int wtot, int bn) {
  int i = blockIdx.x * blockDim.x + threadIdx.x;
  if (i < n4) {
    float4 v = ((const float4*)x)[i];
    unsigned int lo = (unsigned int)f2b(v.x) | ((unsigned int)f2b(v.y) << 16);
    unsigned int hi = (unsigned int)f2b(v.z) | ((unsigned int)f2b(v.w) << 16);
    ((uint2*)xb)[i] = make_uint2(lo, hi);
  } else if (i < n4 + wtot) {
    int j = i - n4;
    int mat = j >> 14, rem = j & 16383, nn = rem >> 7, kk = rem & 127;
    int sidx = (mat << 14) + (kk << 7) + nn;
    Wlt[j] = f2b(Wl[sidx]);
    Wrt[j] = f2b(Wr[sidx]);
  } else if (i < n4 + wtot + bn) {
    int j = i - n4 - wtot;
    float s = g[j] * rsqrtf(rv[j] + BN_EPS);
    sc[j] = s;
    sh[j] = be[j] - rm[j] * s;
  }
}

// ------------- SpMM gather-only: aggb[i] = bf16(inv_deg[i]*sum hb[src]) ----------
// champion config: wave/node, 4 edge-slots x 16 channel-lanes, 16-edge unroll.

__global__ __launch_bounds__(256) void k_spmm_g(
    const unsigned short* __restrict__ hbsrc, const int* __restrict__ row_ptr,
    const int* __restrict__ col, const float* __restrict__ inv_deg,
    unsigned short* __restrict__ aggb, int n) {
  int node = blockIdx.x * 4 + (threadIdx.x >> 6);
  if (node >= n) return;
  int lane = threadIdx.x & 63;
  int slot = lane >> 4, c16 = lane & 15;
  int beg = row_ptr[node], end = row_ptr[node + 1];
  float a0 = 0, a1 = 0, a2 = 0, a3 = 0, a4 = 0, a5 = 0, a6 = 0, a7 = 0;
  const unsigned short* base = hbsrc + (c16 << 3);
  int e = beg;
  for (; e + 16 <= end; e += 16) {
    int s0 = col[e + slot];
    int s1 = col[e + 4 + slot];
    int s2 = col[e + 8 + slot];
    int s3 = col[e + 12 + slot];
    uint4 v0 = *(const uint4*)(base + ((size_t)s0 << 7));
    uint4 v1 = *(const uint4*)(base + ((size_t)s1 << 7));
    uint4 v2 = *(const uint4*)(base + ((size_t)s2 << 7));
    uint4 v3 = *(const uint4*)(base + ((size_t)s3 << 7));
    a0 += bl(v0.x); a1 += bh(v0.x); a2 += bl(v0.y); a3 += bh(v0.y);
    a4 += bl(v0.z); a5 += bh(v0.z); a6 += bl(v0.w); a7 += bh(v0.w);
    a0 += bl(v1.x); a1 += bh(v1.x); a2 += bl(v1.y); a3 += bh(v1.y);
    a4 += bl(v1.z); a5 += bh(v1.z); a6 += bl(v1.w); a7 += bh(v1.w);
    a0 += bl(v2.x); a1 += bh(v2.x); a2 += bl(v2.y); a3 += bh(v2.y);
    a4 += bl(v2.z); a5 += bh(v2.z); a6 += bl(v2.w); a7 += bh(v2.w);
    a0 += bl(v3.x); a1 += bh(v3.x); a2 += bl(v3.y); a3 += bh(v3.y);
    a4 += bl(v3.z); a5 += bh(v3.z); a6 += bl(v3.w); a7 += bh(v3.w);
  }
  for (; e < end; e += 4) {
    int idx = e + slot;
    if (idx < end) {
      int s = col[idx];
      uint4 v = *(const uint4*)(base + ((size_t)s << 7));
      a0 += bl(v.x); a1 += bh(v.x); a2 += bl(v.y); a3 += bh(v.y);
      a4 += bl(v.z); a5 += bh(v.z); a6 += bl(v.w); a7 += bh(v.w);
    }
  }
#pragma unroll
  for (int st = 16; st <= 32; st <<= 1) {
    a0 += __shfl_xor(a0, st); a1 += __shfl_xor(a1, st);
    a2 += __shfl_xor(a2, st); a3 += __shfl_xor(a3, st);
    a4 += __shfl_xor(a4, st); a5 += __shfl_xor(a5, st);
    a6 += __shfl_xor(a6, st); a7 += __shfl_xor(a7, st);
  }
  if (slot == 0) {
    float w = inv_deg[node];
    unsigned int p0 = (unsigned int)f2b(a0 * w) | ((unsigned int)f2b(a1 * w) << 16);
    unsigned int p1 = (unsigned int)f2b(a2 * w) | ((unsigned int)f2b(a3 * w) << 16);
    unsigned int p2 = (unsigned int)f2b(a4 * w) | ((unsigned int)f2b(a5 * w) << 16);
    unsigned int p3 = (unsigned int)f2b(a6 * w) | ((unsigned int)f2b(a7 * w) << 16);
    *(uint4*)(aggb + ((size_t)node << 7) + (c16 << 3)) = make_uint4(p0, p1, p2, p3);
  }
}

// ---- MFMA layer GEMM, weight-stationary, fused BN+ReLU; grid raised for occupancy

__global__ __launch_bounds__(256) void k_gemm3(
    const unsigned short* __restrict__ aggb,  // [n][128] bf16
    const unsigned short* __restrict__ hbsrc, // [n][128] bf16
    const unsigned short* __restrict__ Wlt,   // [128][128] bf16 [out_ch][k]
    const unsigned short* __restrict__ Wrt,
    const float* __restrict__ bias, const float* __restrict__ sc,
    const float* __restrict__ sh, unsigned short* __restrict__ hbo,
    int n, int ngroups) {
  int w = threadIdx.x >> 6;
  int lane = threadIdx.x & 63;
  int l15 = lane & 15, lhi = lane >> 4;

  bf16x8 aL[2][4], aR[2][4];
#pragma unroll
  for (int ms = 0; ms < 2; ++ms) {
    int row = (w << 5) + (ms << 4) + l15;
#pragma unroll
    for (int ks = 0; ks < 4; ++ks) {
      aL[ms][ks] = *(const bf16x8*)(Wlt + (row << 7) + (ks << 5) + (lhi << 3));
      aR[ms][ks] = *(const bf16x8*)(Wrt + (row << 7) + (ks << 5) + (lhi << 3));
    }
  }
  float4 bi[2], scv[2], shv[2];
#pragma unroll
  for (int ms = 0; ms < 2; ++ms) {
    int ch = (w << 5) + (ms << 4) + (lhi << 2);
    bi[ms] = *(const float4*)(bias + ch);
    scv[ms] = *(const float4*)(sc + ch);
    shv[ms] = *(const float4*)(sh + ch);
  }

  for (int g = blockIdx.x; g < ngroups; g += gridDim.x) {
    int node = (g << 4) + l15;
    bool ok = node < n;
    int nsafe = ok ? node : 0;
    const unsigned short* arow = aggb + ((size_t)nsafe << 7) + (lhi << 3);
    const unsigned short* hrow = hbsrc + ((size_t)nsafe << 7) + (lhi << 3);
    bf16x8 bA0 = *(const bf16x8*)(arow);
    bf16x8 bA1 = *(const bf16x8*)(arow + 32);
    bf16x8 bA2 = *(const bf16x8*)(arow + 64);
    bf16x8 bA3 = *(const bf16x8*)(arow + 96);
    bf16x8 bH0 = *(const bf16x8*)(hrow);
    bf16x8 bH1 = *(const bf16x8*)(hrow + 32);
    bf16x8 bH2 = *(const bf16x8*)(hrow + 64);
    bf16x8 bH3 = *(const bf16x8*)(hrow + 96);
    f32x4 acc[2];
#pragma unroll
    for (int ms = 0; ms < 2; ++ms) acc[ms] = (f32x4)(0.f);
#pragma unroll
    for (int ms = 0; ms < 2; ++ms) {
      acc[ms] = __builtin_amdgcn_mfma_f32_16x16x32_bf16(aL[ms][0], bA0, acc[ms], 0, 0, 0);
      acc[ms] = __builtin_amdgcn_mfma_f32_16x16x32_bf16(aL[ms][1], bA1, acc[ms], 0, 0, 0);
      acc[ms] = __builtin_amdgcn_mfma_f32_16x16x32_bf16(aL[ms][2], bA2, acc[ms], 0, 0, 0);
      acc[ms] = __builtin_amdgcn_mfma_f32_16x16x32_bf16(aL[ms][3], bA3, acc[ms], 0, 0, 0);
      acc[ms] = __builtin_amdgcn_mfma_f32_16x16x32_bf16(aR[ms][0], bH0, acc[ms], 0, 0, 0);
      acc[ms] = __builtin_amdgcn_mfma_f32_16x16x32_bf16(aR[ms][1], bH1, acc[ms], 0, 0, 0);
      acc[ms] = __builtin_amdgcn_mfma_f32_16x16x32_bf16(aR[ms][2], bH2, acc[ms], 0, 0, 0);
      acc[ms] = __builtin_amdgcn_mfma_f32_16x16x32_bf16(aR[ms][3], bH3, acc[ms], 0, 0, 0);
    }
    if (ok) {
#pragma unroll
      for (int ms = 0; ms < 2; ++ms) {
        int ch = (w << 5) + (ms << 4) + (lhi << 2);
        float o0 = fmaxf((acc[ms][0] + bi[ms].x) * scv[ms].x + shv[ms].x, 0.f);
        float o1 = fmaxf((acc[ms][1] + bi[ms].y) * scv[ms].y + shv[ms].y, 0.f);
        float o2 = fmaxf((acc[ms][2] + bi[ms].z) * scv[ms].z + shv[ms].z, 0.f);
        float o3 = fmaxf((acc[ms][3] + bi[ms].w) * scv[ms].w + shv[ms].w, 0.f);
        unsigned int lo = (unsigned int)f2b(o0) | ((unsigned int)f2b(o1) << 16);
        unsigned int hi = (unsigned int)f2b(o2) | ((unsigned int)f2b(o3) << 16);
        *(uint2*)(hbo + ((size_t)node << 7) + ch) = make_uint2(lo, hi);
      }
    }
  }
}

// ---------------- final layer ----------------

__global__ void k_pq(const unsigned short* __restrict__ hb, const float* __restrict__ Wl_out,
                     const float* __restrict__ Wr_out, float* __restrict__ p,
                     float* __restrict__ q, int n) {
  int node = blockIdx.x * 4 + (threadIdx.x >> 6);
  if (node >= n) return;
  int lane = threadIdx.x & 63;
  unsigned int hv = *(const unsigned int*)(hb + ((size_t)node << 7) + (lane << 1));
  float hx = bl(hv), hy = bh(hv);
  float4 wl = *(const float4*)(Wl_out + (lane << 2)); // rows 2l,2l+1; cols 0,1
  float4 wr = *(const float4*)(Wr_out + (lane << 2));
  float p0 = hx * wl.x + hy * wl.z;
  float p1 = hx * wl.y + hy * wl.w;
  float q0 = hx * wr.x + hy * wr.z;
  float q1 = hx * wr.y + hy * wr.w;
#pragma unroll
  for (int off = 32; off > 0; off >>= 1) {
    p0 += __shfl_xor(p0, off, 64);
    p1 += __shfl_xor(p1, off, 64);
    q0 += __shfl_xor(q0, off, 64);
    q1 += __shfl_xor(q1, off, 64);
  }
  if (lane == 0) {
    *(float2*)(p + (size_t)node * 2) = make_float2(p0, p1);
    *(float2*)(q + (size_t)node * 2) = make_float2(q0, q1);
  }
}

// fused: per-node final conv output + segmented-scan mean-pool (batch is sorted)
__global__ void k_spmm2p(const float* __restrict__ p, const float* __restrict__ q,
                         const int* __restrict__ row_ptr, const int* __restrict__ col,
                         const float* __restrict__ inv_deg, const float* __restrict__ b_out,
                         const int* __restrict__ batch, float* __restrict__ out,
                         float* __restrict__ gcnt, int n) {
  int i = blockIdx.x * blockDim.x + threadIdx.x;
  int lane = threadIdx.x & 63;
  bool valid = i < n;
  float o0 = 0.f, o1 = 0.f;
  int g = -1;
  if (valid) {
    int beg = row_ptr[i], end = row_ptr[i + 1];
    float a0 = 0.f, a1 = 0.f, b0 = 0.f, b1 = 0.f;
    int e = beg;
    for (; e + 2 <= end; e += 2) {
      float2 v0 = *(const float2*)(p + (size_t)col[e] * 2);
      float2 v1 = *(const float2*)(p + (size_t)col[e + 1] * 2);
      a0 += v0.x; a1 += v0.y; b0 += v1.x; b1 += v1.y;
    }
    if (e < end) {
      float2 v = *(const float2*)(p + (size_t)col[e] * 2);
      a0 += v.x; a1 += v.y;
    }
    float w = inv_deg[i];
    float2 qv = *(const float2*)(q + (size_t)i * 2);
    o0 = (a0 + b0) * w + qv.x + b_out[0];
    o1 = (a1 + b1) * w + qv.y + b_out[1];
    g = batch[i];
  }
  float s0 = o0, s1 = o1;
#pragma unroll
  for (int off = 1; off < 64; off <<= 1) {
    float y0 = __shfl_up(s0, off, 64);
    float y1 = __shfl_up(s1, off, 64);
    if (lane >= off) { s0 += y0; s1 += y1; }
  }
  int gprev = __shfl_up(g, 1, 64);
  int gnext = __shfl_down(g, 1, 64);
  bool is_start = (lane == 0) || (g != gprev);
  bool is_end = valid && ((lane == 63) || (g != gnext));
  int startl = is_start ? lane : 0;
#pragma unroll
  for (int off = 1; off < 64; off <<= 1) {
    int y = __shfl_up(startl, off, 64);
    if (lane >= off) startl = max(startl, y);
  }
  int prevl = startl > 0 ? startl - 1 : 0;
  float t0 = __shfl(s0, prevl, 64);
  float t1 = __shfl(s1, prevl, 64);
  if (is_end) {
    float p0 = startl > 0 ? t0 : 0.f;
    float p1 = startl > 0 ? t1 : 0.f;
    atomicAdd(&out[g * 2], s0 - p0);
    atomicAdd(&out[g * 2 + 1], s1 - p1);
    atomicAdd(&gcnt[g], (float)(lane - startl + 1));
  }
}

__global__ void k_div(float* __restrict__ out, const float* __restrict__ gcnt, int ng) {
  int i = blockIdx.x * blockDim.x + threadIdx.x;
  if (i < ng * 2) out[i] /= fmaxf(gcnt[i >> 1], 1.0f);
}

// ---------------- launch ----------------

extern "C" void kernel_launch(void* const* d_in, const int* in_sizes, int n_in,
                              void* d_out, int out_size, void* d_ws, size_t ws_size,
                              hipStream_t stream) {
  const float* x = (const float*)d_in[0];
  const float* Wl = (const float*)d_in[1];
  const float* Wr = (const float*)d_in[2];
  const float* b = (const float*)d_in[3];
  const float* gamma = (const float*)d_in[4];
  const float* beta = (const float*)d_in[5];
  const float* rmean = (const float*)d_in[6];
  const float* rvar = (const float*)d_in[7];
  const float* Wl_out = (const float*)d_in[8];
  const float* Wr_out = (const float*)d_in[9];
  const float* b_out = (const float*)d_in[10];
  const int* eidx = (const int*)d_in[11];
  const int* batch = (const int*)d_in[12];

  const int N = in_sizes[0] / HID;
  const int E = in_sizes[11] / 2;
  const int L = in_sizes[1] / (HID * HID);
  const int NG = out_size / 2;
  const int NB = (N + 255) >> 8;  // nodes/bucket = 256; requires N <= 65536
  const int NGRP = (N + 15) >> 4;
  const int* src = eidx;
  const int* dst = eidx + E;

  char* ws = (char*)d_ws;
  size_t off = 0;
  auto alloc = [&](size_t bytes) {
    void* ptr = ws + off;
    off += (bytes + 255) & ~(size_t)255;
    return ptr;
  };
  int* row_ptr = (int*)alloc((size_t)(N + 1) * 4);
  int* bcnt = (int*)alloc((size_t)NB * 4);
  int* bbase = (int*)alloc((size_t)(NB + 1) * 4);
  int* bcur = (int*)alloc((size_t)NB * 4);
  int* col = (int*)alloc((size_t)E * 4);
  float* inv_deg = (float*)alloc((size_t)N * 4);
  unsigned short* xb = (unsigned short*)alloc((size_t)N * HID * 2);
  unsigned short* hb0 = (unsigned short*)alloc((size_t)N * HID * 2);
  unsigned short* hb1 = (unsigned short*)alloc((size_t)N * HID * 2);
  unsigned short* aggb = (unsigned short*)alloc((size_t)N * HID * 2);
  unsigned short* Wlt = (unsigned short*)alloc((size_t)L * HID * HID * 2);
  unsigned short* Wrt = (unsigned short*)alloc((size_t)L * HID * HID * 2);
  float* sc = (float*)alloc((size_t)L * HID * 4);
  float* sh = (float*)alloc((size_t)L * HID * 4);
  float* p = (float*)alloc((size_t)N * 2 * 4);
  float* q = (float*)alloc((size_t)N * 2 * 4);
  float* gcnt = (float*)alloc((size_t)NG * 4);
  uint2* binned = (uint2*)alloc((size_t)E * 8);  // dead after k_bfill

  hipMemsetAsync(bcnt, 0, (size_t)NB * 4, stream);
  k_bhist<<<256, 256, 0, stream>>>(dst, bcnt, E, NB);
  k_bscan<<<1, 256, 0, stream>>>(bcnt, bbase, bcur, NB);
  k_bscatter<<<256, 256, 0, stream>>>(src, dst, bcur, binned, E);
  k_bfill<<<NB, 256, 0, stream>>>(binned, bbase, row_ptr, inv_deg, col, N, NB);

  const int n4 = N * HID / 4;
  const int wtot = L * HID * HID;
  const int bn = L * HID;
  k_prep<<<(n4 + wtot + bn + 255) / 256, 256, 0, stream>>>(
      x, xb, Wl, Wr, Wlt, Wrt, gamma, beta, rmean, rvar, sc, sh, n4, wtot, bn);

  const unsigned short* hin = xb;
  for (int l = 0; l < L; ++l) {
    unsigned short* hnext = (l & 1) ? hb1 : hb0;
    k_spmm_g<<<(N + 3) / 4, 256, 0, stream>>>(hin, row_ptr, col, inv_deg, aggb, N);
    k_gemm3<<<1536, 256, 0, stream>>>(
        aggb, hin, Wlt + (size_t)l * HID * HID, Wrt + (size_t)l * HID * HID,
        b + (size_t)l * HID, sc + (size_t)l * HID, sh + (size_t)l * HID,
        hnext, N, NGRP);
    hin = hnext;
  }
  k_pq<<<(N + 3) / 4, 256, 0, stream>>>(hin, Wl_out, Wr_out, p, q, N);
  hipMemsetAsync(d_out, 0, (size_t)out_size * 4, stream);
  hipMemsetAsync(gcnt, 0, (size_t)NG * 4, stream);
  k_spmm2p<<<(N + 255) / 256, 256, 0, stream>>>(
      p, q, row_ptr, col, inv_deg, b_out, batch, (float*)d_out, gcnt, N);
  k_div<<<(NG * 2 + 255) / 256, 256, 0, stream>>>((float*)d_out, gcnt, NG);
}

// Round 15
// 446.192 us; speedup vs baseline: 1.1806x; 1.1191x over previous
//
#include <hip/hip_runtime.h>

#define HID 128
#define BN_EPS 1e-5f

typedef short bf16x8 __attribute__((ext_vector_type(8)));
typedef float f32x4 __attribute__((ext_vector_type(4)));

__device__ inline unsigned short f2b(float f) {  // f32 -> bf16 RNE
  unsigned int u = __float_as_uint(f);
  unsigned int r = (u + 0x7fffu + ((u >> 16) & 1u)) >> 16;
  return (unsigned short)r;
}
__device__ inline float bl(unsigned int v) { return __uint_as_float(v << 16); }
__device__ inline float bh(unsigned int v) { return __uint_as_float(v & 0xffff0000u); }

// ---------------- bucketed CSR build (bucket = dst >> 8, 256 nodes/bucket) -------

__global__ void k_bhist(const int* __restrict__ dst, int* __restrict__ bcnt, int e, int nb) {
  __shared__ int h[256];
  for (int i = threadIdx.x; i < 256; i += blockDim.x) h[i] = 0;
  __syncthreads();
  int stride = gridDim.x * blockDim.x;
  for (int i = blockIdx.x * blockDim.x + threadIdx.x; i < e; i += stride)
    atomicAdd(&h[dst[i] >> 8], 1);
  __syncthreads();
  for (int i = threadIdx.x; i < nb; i += blockDim.x)
    if (h[i]) atomicAdd(&bcnt[i], h[i]);
}

// single block; nb <= 256
__global__ void k_bscan(const int* __restrict__ bcnt, int* __restrict__ base,
                        int* __restrict__ cur, int nb) {
  __shared__ int ws[4];
  int t = threadIdx.x;
  int v = (t < nb) ? bcnt[t] : 0;
  int lane = t & 63, wid = t >> 6;
  int x = v;
#pragma unroll
  for (int off = 1; off < 64; off <<= 1) {
    int y = __shfl_up(x, off, 64);
    if (lane >= off) x += y;
  }
  if (lane == 63) ws[wid] = x;
  __syncthreads();
  int add = 0;
  for (int w = 0; w < wid; ++w) add += ws[w];
  int incl = x + add;
  int excl = incl - v;
  if (t < nb) { base[t] = excl; cur[t] = excl; }
  if (t == nb - 1) base[nb] = incl;
}

__global__ void k_bscatter(const int* __restrict__ src, const int* __restrict__ dst,
                           int* __restrict__ cur, uint2* __restrict__ binned, int e) {
  __shared__ int bc[256];
  __shared__ int bo[256];
  int nchunk = (e + gridDim.x - 1) / gridDim.x;
  int c0 = blockIdx.x * nchunk;
  int c1 = min(c0 + nchunk, e);
  for (int i = threadIdx.x; i < 256; i += blockDim.x) bc[i] = 0;
  __syncthreads();
  for (int i = c0 + threadIdx.x; i < c1; i += blockDim.x)
    atomicAdd(&bc[dst[i] >> 8], 1);
  __syncthreads();
  for (int i = threadIdx.x; i < 256; i += blockDim.x) {
    int c = bc[i];
    bo[i] = c ? atomicAdd(&cur[i], c) : 0;
    bc[i] = 0;
  }
  __syncthreads();
  for (int i = c0 + threadIdx.x; i < c1; i += blockDim.x) {
    int d = dst[i];
    int b = d >> 8;
    int pos = bo[b] + atomicAdd(&bc[b], 1);
    binned[pos] = make_uint2((unsigned)src[i], (unsigned)d);
  }
}

// one block per bucket: row_ptr, inv_deg, col — all scatters LDS/L2-local
__global__ __launch_bounds__(256) void k_bfill(
    const uint2* __restrict__ binned, const int* __restrict__ base,
    int* __restrict__ row_ptr, float* __restrict__ inv_deg,
    int* __restrict__ col, int n, int nb) {
  __shared__ int cnt[256];
  __shared__ int cur[256];
  __shared__ int ws[4];
  int b = blockIdx.x;
  int t = threadIdx.x;
  int n0 = b << 8;
  int e0 = base[b], e1 = base[b + 1];
  cnt[t] = 0;
  __syncthreads();
  for (int i = e0 + t; i < e1; i += 256)
    atomicAdd(&cnt[binned[i].y & 255], 1);
  __syncthreads();
  int v = cnt[t];
  int lane = t & 63, wid = t >> 6;
  int x = v;
#pragma unroll
  for (int off = 1; off < 64; off <<= 1) {
    int y = __shfl_up(x, off, 64);
    if (lane >= off) x += y;
  }
  if (lane == 63) ws[wid] = x;
  __syncthreads();
  int add = 0;
  for (int w = 0; w < wid; ++w) add += ws[w];
  int excl = x - v + add;
  int node = n0 + t;
  if (node < n) {
    row_ptr[node] = e0 + excl;
    inv_deg[node] = 1.0f / (float)max(v, 1);
  }
  cur[t] = e0 + excl;
  __syncthreads();
  for (int i = e0 + t; i < e1; i += 256) {
    uint2 pr = binned[i];
    int pos = atomicAdd(&cur[pr.y & 255], 1);
    col[pos] = (int)pr.x;
  }
  if (b == 0 && t == 0) row_ptr[n] = base[nb];
}

// ------- merged prep: x->bf16, W->bf16 transposed, BN fold (one launch) ---------

__global__ void k_prep(const float* __restrict__ x, unsigned short* __restrict__ xb,
                       const float* __restrict__ Wl, const float* __restrict__ Wr,
                       unsigned short* __restrict__ Wlt, unsigned short* __restrict__ Wrt,
                       const float* __restrict__ g, const float* __restrict__ be,
                       const float* __restrict__ rm, const float* __restrict__ rv,
                       float* __restrict__ sc, float* __restrict__ sh,
                       int n4, int wtot, int bn) {
  int i = blockIdx.x * blockDim.x + threadIdx.x;
  if (i < n4) {
    float4 v = ((const float4*)x)[i];
    unsigned int lo = (unsigned int)f2b(v.x) | ((unsigned int)f2b(v.y) << 16);
    unsigned int hi = (unsigned int)f2b(v.z) | ((unsigned int)f2b(v.w) << 16);
    ((uint2*)xb)[i] = make_uint2(lo, hi);
  } else if (i < n4 + wtot) {
    int j = i - n4;
    int mat = j >> 14, rem = j & 16383, nn = rem >> 7, kk = rem & 127;
    int sidx = (mat << 14) + (kk << 7) + nn;
    Wlt[j] = f2b(Wl[sidx]);
    Wrt[j] = f2b(Wr[sidx]);
  } else if (i < n4 + wtot + bn) {
    int j = i - n4 - wtot;
    float s = g[j] * rsqrtf(rv[j] + BN_EPS);
    sc[j] = s;
    sh[j] = be[j] - rm[j] * s;
  }
}

// ------------- SpMM gather-only: aggb[i] = bf16(inv_deg[i]*sum hb[src]) ----------
// champion config: wave/node, 4 edge-slots x 16 channel-lanes, 16-edge unroll.

__global__ __launch_bounds__(256) void k_spmm_g(
    const unsigned short* __restrict__ hbsrc, const int* __restrict__ row_ptr,
    const int* __restrict__ col, const float* __restrict__ inv_deg,
    unsigned short* __restrict__ aggb, int n) {
  int node = blockIdx.x * 4 + (threadIdx.x >> 6);
  if (node >= n) return;
  int lane = threadIdx.x & 63;
  int slot = lane >> 4, c16 = lane & 15;
  int beg = row_ptr[node], end = row_ptr[node + 1];
  float a0 = 0, a1 = 0, a2 = 0, a3 = 0, a4 = 0, a5 = 0, a6 = 0, a7 = 0;
  const unsigned short* base = hbsrc + (c16 << 3);
  int e = beg;
  for (; e + 16 <= end; e += 16) {
    int s0 = col[e + slot];
    int s1 = col[e + 4 + slot];
    int s2 = col[e + 8 + slot];
    int s3 = col[e + 12 + slot];
    uint4 v0 = *(const uint4*)(base + ((size_t)s0 << 7));
    uint4 v1 = *(const uint4*)(base + ((size_t)s1 << 7));
    uint4 v2 = *(const uint4*)(base + ((size_t)s2 << 7));
    uint4 v3 = *(const uint4*)(base + ((size_t)s3 << 7));
    a0 += bl(v0.x); a1 += bh(v0.x); a2 += bl(v0.y); a3 += bh(v0.y);
    a4 += bl(v0.z); a5 += bh(v0.z); a6 += bl(v0.w); a7 += bh(v0.w);
    a0 += bl(v1.x); a1 += bh(v1.x); a2 += bl(v1.y); a3 += bh(v1.y);
    a4 += bl(v1.z); a5 += bh(v1.z); a6 += bl(v1.w); a7 += bh(v1.w);
    a0 += bl(v2.x); a1 += bh(v2.x); a2 += bl(v2.y); a3 += bh(v2.y);
    a4 += bl(v2.z); a5 += bh(v2.z); a6 += bl(v2.w); a7 += bh(v2.w);
    a0 += bl(v3.x); a1 += bh(v3.x); a2 += bl(v3.y); a3 += bh(v3.y);
    a4 += bl(v3.z); a5 += bh(v3.z); a6 += bl(v3.w); a7 += bh(v3.w);
  }
  for (; e < end; e += 4) {
    int idx = e + slot;
    if (idx < end) {
      int s = col[idx];
      uint4 v = *(const uint4*)(base + ((size_t)s << 7));
      a0 += bl(v.x); a1 += bh(v.x); a2 += bl(v.y); a3 += bh(v.y);
      a4 += bl(v.z); a5 += bh(v.z); a6 += bl(v.w); a7 += bh(v.w);
    }
  }
#pragma unroll
  for (int st = 16; st <= 32; st <<= 1) {
    a0 += __shfl_xor(a0, st); a1 += __shfl_xor(a1, st);
    a2 += __shfl_xor(a2, st); a3 += __shfl_xor(a3, st);
    a4 += __shfl_xor(a4, st); a5 += __shfl_xor(a5, st);
    a6 += __shfl_xor(a6, st); a7 += __shfl_xor(a7, st);
  }
  if (slot == 0) {
    float w = inv_deg[node];
    unsigned int p0 = (unsigned int)f2b(a0 * w) | ((unsigned int)f2b(a1 * w) << 16);
    unsigned int p1 = (unsigned int)f2b(a2 * w) | ((unsigned int)f2b(a3 * w) << 16);
    unsigned int p2 = (unsigned int)f2b(a4 * w) | ((unsigned int)f2b(a5 * w) << 16);
    unsigned int p3 = (unsigned int)f2b(a6 * w) | ((unsigned int)f2b(a7 * w) << 16);
    *(uint4*)(aggb + ((size_t)node << 7) + (c16 << 3)) = make_uint4(p0, p1, p2, p3);
  }
}

// ---- MFMA layer GEMM, weight-stationary, fused BN+ReLU (512 blocks = optimum) ---

__global__ __launch_bounds__(256) void k_gemm3(
    const unsigned short* __restrict__ aggb,  // [n][128] bf16
    const unsigned short* __restrict__ hbsrc, // [n][128] bf16
    const unsigned short* __restrict__ Wlt,   // [128][128] bf16 [out_ch][k]
    const unsigned short* __restrict__ Wrt,
    const float* __restrict__ bias, const float* __restrict__ sc,
    const float* __restrict__ sh, unsigned short* __restrict__ hbo,
    int n, int ngroups) {
  int w = threadIdx.x >> 6;
  int lane = threadIdx.x & 63;
  int l15 = lane & 15, lhi = lane >> 4;

  bf16x8 aL[2][4], aR[2][4];
#pragma unroll
  for (int ms = 0; ms < 2; ++ms) {
    int row = (w << 5) + (ms << 4) + l15;
#pragma unroll
    for (int ks = 0; ks < 4; ++ks) {
      aL[ms][ks] = *(const bf16x8*)(Wlt + (row << 7) + (ks << 5) + (lhi << 3));
      aR[ms][ks] = *(const bf16x8*)(Wrt + (row << 7) + (ks << 5) + (lhi << 3));
    }
  }
  float4 bi[2], scv[2], shv[2];
#pragma unroll
  for (int ms = 0; ms < 2; ++ms) {
    int ch = (w << 5) + (ms << 4) + (lhi << 2);
    bi[ms] = *(const float4*)(bias + ch);
    scv[ms] = *(const float4*)(sc + ch);
    shv[ms] = *(const float4*)(sh + ch);
  }

  for (int g = blockIdx.x; g < ngroups; g += gridDim.x) {
    int node = (g << 4) + l15;
    bool ok = node < n;
    int nsafe = ok ? node : 0;
    const unsigned short* arow = aggb + ((size_t)nsafe << 7) + (lhi << 3);
    const unsigned short* hrow = hbsrc + ((size_t)nsafe << 7) + (lhi << 3);
    bf16x8 bA0 = *(const bf16x8*)(arow);
    bf16x8 bA1 = *(const bf16x8*)(arow + 32);
    bf16x8 bA2 = *(const bf16x8*)(arow + 64);
    bf16x8 bA3 = *(const bf16x8*)(arow + 96);
    bf16x8 bH0 = *(const bf16x8*)(hrow);
    bf16x8 bH1 = *(const bf16x8*)(hrow + 32);
    bf16x8 bH2 = *(const bf16x8*)(hrow + 64);
    bf16x8 bH3 = *(const bf16x8*)(hrow + 96);
    f32x4 acc[2];
#pragma unroll
    for (int ms = 0; ms < 2; ++ms) acc[ms] = (f32x4)(0.f);
#pragma unroll
    for (int ms = 0; ms < 2; ++ms) {
      acc[ms] = __builtin_amdgcn_mfma_f32_16x16x32_bf16(aL[ms][0], bA0, acc[ms], 0, 0, 0);
      acc[ms] = __builtin_amdgcn_mfma_f32_16x16x32_bf16(aL[ms][1], bA1, acc[ms], 0, 0, 0);
      acc[ms] = __builtin_amdgcn_mfma_f32_16x16x32_bf16(aL[ms][2], bA2, acc[ms], 0, 0, 0);
      acc[ms] = __builtin_amdgcn_mfma_f32_16x16x32_bf16(aL[ms][3], bA3, acc[ms], 0, 0, 0);
      acc[ms] = __builtin_amdgcn_mfma_f32_16x16x32_bf16(aR[ms][0], bH0, acc[ms], 0, 0, 0);
      acc[ms] = __builtin_amdgcn_mfma_f32_16x16x32_bf16(aR[ms][1], bH1, acc[ms], 0, 0, 0);
      acc[ms] = __builtin_amdgcn_mfma_f32_16x16x32_bf16(aR[ms][2], bH2, acc[ms], 0, 0, 0);
      acc[ms] = __builtin_amdgcn_mfma_f32_16x16x32_bf16(aR[ms][3], bH3, acc[ms], 0, 0, 0);
    }
    if (ok) {
#pragma unroll
      for (int ms = 0; ms < 2; ++ms) {
        int ch = (w << 5) + (ms << 4) + (lhi << 2);
        float o0 = fmaxf((acc[ms][0] + bi[ms].x) * scv[ms].x + shv[ms].x, 0.f);
        float o1 = fmaxf((acc[ms][1] + bi[ms].y) * scv[ms].y + shv[ms].y, 0.f);
        float o2 = fmaxf((acc[ms][2] + bi[ms].z) * scv[ms].z + shv[ms].z, 0.f);
        float o3 = fmaxf((acc[ms][3] + bi[ms].w) * scv[ms].w + shv[ms].w, 0.f);
        unsigned int lo = (unsigned int)f2b(o0) | ((unsigned int)f2b(o1) << 16);
        unsigned int hi = (unsigned int)f2b(o2) | ((unsigned int)f2b(o3) << 16);
        *(uint2*)(hbo + ((size_t)node << 7) + ch) = make_uint2(lo, hi);
      }
    }
  }
}

// ---------------- final layer ----------------

__global__ void k_pq(const unsigned short* __restrict__ hb, const float* __restrict__ Wl_out,
                     const float* __restrict__ Wr_out, float* __restrict__ p,
                     float* __restrict__ q, int n) {
  int node = blockIdx.x * 4 + (threadIdx.x >> 6);
  if (node >= n) return;
  int lane = threadIdx.x & 63;
  unsigned int hv = *(const unsigned int*)(hb + ((size_t)node << 7) + (lane << 1));
  float hx = bl(hv), hy = bh(hv);
  float4 wl = *(const float4*)(Wl_out + (lane << 2)); // rows 2l,2l+1; cols 0,1
  float4 wr = *(const float4*)(Wr_out + (lane << 2));
  float p0 = hx * wl.x + hy * wl.z;
  float p1 = hx * wl.y + hy * wl.w;
  float q0 = hx * wr.x + hy * wr.z;
  float q1 = hx * wr.y + hy * wr.w;
#pragma unroll
  for (int off = 32; off > 0; off >>= 1) {
    p0 += __shfl_xor(p0, off, 64);
    p1 += __shfl_xor(p1, off, 64);
    q0 += __shfl_xor(q0, off, 64);
    q1 += __shfl_xor(q1, off, 64);
  }
  if (lane == 0) {
    *(float2*)(p + (size_t)node * 2) = make_float2(p0, p1);
    *(float2*)(q + (size_t)node * 2) = make_float2(q0, q1);
  }
}

// fused: per-node final conv output + segmented-scan mean-pool (batch is sorted)
__global__ void k_spmm2p(const float* __restrict__ p, const float* __restrict__ q,
                         const int* __restrict__ row_ptr, const int* __restrict__ col,
                         const float* __restrict__ inv_deg, const float* __restrict__ b_out,
                         const int* __restrict__ batch, float* __restrict__ out,
                         float* __restrict__ gcnt, int n) {
  int i = blockIdx.x * blockDim.x + threadIdx.x;
  int lane = threadIdx.x & 63;
  bool valid = i < n;
  float o0 = 0.f, o1 = 0.f;
  int g = -1;
  if (valid) {
    int beg = row_ptr[i], end = row_ptr[i + 1];
    float a0 = 0.f, a1 = 0.f, b0 = 0.f, b1 = 0.f;
    int e = beg;
    for (; e + 2 <= end; e += 2) {
      float2 v0 = *(const float2*)(p + (size_t)col[e] * 2);
      float2 v1 = *(const float2*)(p + (size_t)col[e + 1] * 2);
      a0 += v0.x; a1 += v0.y; b0 += v1.x; b1 += v1.y;
    }
    if (e < end) {
      float2 v = *(const float2*)(p + (size_t)col[e] * 2);
      a0 += v.x; a1 += v.y;
    }
    float w = inv_deg[i];
    float2 qv = *(const float2*)(q + (size_t)i * 2);
    o0 = (a0 + b0) * w + qv.x + b_out[0];
    o1 = (a1 + b1) * w + qv.y + b_out[1];
    g = batch[i];
  }
  float s0 = o0, s1 = o1;
#pragma unroll
  for (int off = 1; off < 64; off <<= 1) {
    float y0 = __shfl_up(s0, off, 64);
    float y1 = __shfl_up(s1, off, 64);
    if (lane >= off) { s0 += y0; s1 += y1; }
  }
  int gprev = __shfl_up(g, 1, 64);
  int gnext = __shfl_down(g, 1, 64);
  bool is_start = (lane == 0) || (g != gprev);
  bool is_end = valid && ((lane == 63) || (g != gnext));
  int startl = is_start ? lane : 0;
#pragma unroll
  for (int off = 1; off < 64; off <<= 1) {
    int y = __shfl_up(startl, off, 64);
    if (lane >= off) startl = max(startl, y);
  }
  int prevl = startl > 0 ? startl - 1 : 0;
  float t0 = __shfl(s0, prevl, 64);
  float t1 = __shfl(s1, prevl, 64);
  if (is_end) {
    float p0 = startl > 0 ? t0 : 0.f;
    float p1 = startl > 0 ? t1 : 0.f;
    atomicAdd(&out[g * 2], s0 - p0);
    atomicAdd(&out[g * 2 + 1], s1 - p1);
    atomicAdd(&gcnt[g], (float)(lane - startl + 1));
  }
}

__global__ void k_div(float* __restrict__ out, const float* __restrict__ gcnt, int ng) {
  int i = blockIdx.x * blockDim.x + threadIdx.x;
  if (i < ng * 2) out[i] /= fmaxf(gcnt[i >> 1], 1.0f);
}

// ---------------- launch ----------------

extern "C" void kernel_launch(void* const* d_in, const int* in_sizes, int n_in,
                              void* d_out, int out_size, void* d_ws, size_t ws_size,
                              hipStream_t stream) {
  const float* x = (const float*)d_in[0];
  const float* Wl = (const float*)d_in[1];
  const float* Wr = (const float*)d_in[2];
  const float* b = (const float*)d_in[3];
  const float* gamma = (const float*)d_in[4];
  const float* beta = (const float*)d_in[5];
  const float* rmean = (const float*)d_in[6];
  const float* rvar = (const float*)d_in[7];
  const float* Wl_out = (const float*)d_in[8];
  const float* Wr_out = (const float*)d_in[9];
  const float* b_out = (const float*)d_in[10];
  const int* eidx = (const int*)d_in[11];
  const int* batch = (const int*)d_in[12];

  const int N = in_sizes[0] / HID;
  const int E = in_sizes[11] / 2;
  const int L = in_sizes[1] / (HID * HID);
  const int NG = out_size / 2;
  const int NB = (N + 255) >> 8;  // nodes/bucket = 256; requires N <= 65536
  const int NGRP = (N + 15) >> 4;
  const int* src = eidx;
  const int* dst = eidx + E;

  char* ws = (char*)d_ws;
  size_t off = 0;
  auto alloc = [&](size_t bytes) {
    void* ptr = ws + off;
    off += (bytes + 255) & ~(size_t)255;
    return ptr;
  };
  int* row_ptr = (int*)alloc((size_t)(N + 1) * 4);
  int* bcnt = (int*)alloc((size_t)NB * 4);
  int* bbase = (int*)alloc((size_t)(NB + 1) * 4);
  int* bcur = (int*)alloc((size_t)NB * 4);
  int* col = (int*)alloc((size_t)E * 4);
  float* inv_deg = (float*)alloc((size_t)N * 4);
  unsigned short* xb = (unsigned short*)alloc((size_t)N * HID * 2);
  unsigned short* hb0 = (unsigned short*)alloc((size_t)N * HID * 2);
  unsigned short* hb1 = (unsigned short*)alloc((size_t)N * HID * 2);
  unsigned short* aggb = (unsigned short*)alloc((size_t)N * HID * 2);
  unsigned short* Wlt = (unsigned short*)alloc((size_t)L * HID * HID * 2);
  unsigned short* Wrt = (unsigned short*)alloc((size_t)L * HID * HID * 2);
  float* sc = (float*)alloc((size_t)L * HID * 4);
  float* sh = (float*)alloc((size_t)L * HID * 4);
  float* p = (float*)alloc((size_t)N * 2 * 4);
  float* q = (float*)alloc((size_t)N * 2 * 4);
  float* gcnt = (float*)alloc((size_t)NG * 4);
  uint2* binned = (uint2*)alloc((size_t)E * 8);  // dead after k_bfill

  hipMemsetAsync(bcnt, 0, (size_t)NB * 4, stream);
  k_bhist<<<256, 256, 0, stream>>>(dst, bcnt, E, NB);
  k_bscan<<<1, 256, 0, stream>>>(bcnt, bbase, bcur, NB);
  k_bscatter<<<256, 256, 0, stream>>>(src, dst, bcur, binned, E);
  k_bfill<<<NB, 256, 0, stream>>>(binned, bbase, row_ptr, inv_deg, col, N, NB);

  const int n4 = N * HID / 4;
  const int wtot = L * HID * HID;
  const int bn = L * HID;
  k_prep<<<(n4 + wtot + bn + 255) / 256, 256, 0, stream>>>(
      x, xb, Wl, Wr, Wlt, Wrt, gamma, beta, rmean, rvar, sc, sh, n4, wtot, bn);

  const unsigned short* hin = xb;
  for (int l = 0; l < L; ++l) {
    unsigned short* hnext = (l & 1) ? hb1 : hb0;
    k_spmm_g<<<(N + 3) / 4, 256, 0, stream>>>(hin, row_ptr, col, inv_deg, aggb, N);
    k_gemm3<<<512, 256, 0, stream>>>(
        aggb, hin, Wlt + (size_t)l * HID * HID, Wrt + (size_t)l * HID * HID,
        b + (size_t)l * HID, sc + (size_t)l * HID, sh + (size_t)l * HID,
        hnext, N, NGRP);
    hin = hnext;
  }
  k_pq<<<(N + 3) / 4, 256, 0, stream>>>(hin, Wl_out, Wr_out, p, q, N);
  hipMemsetAsync(d_out, 0, (size_t)out_size * 4, stream);
  hipMemsetAsync(gcnt, 0, (size_t)NG * 4, stream);
  k_spmm2p<<<(N + 255) / 256, 256, 0, stream>>>(
      p, q, row_ptr, col, inv_deg, b_out, batch, (float*)d_out, gcnt, N);
  k_div<<<(NG * 2 + 255) / 256, 256, 0, stream>>>((float*)d_out, gcnt, NG);
}